// Round 11
// baseline (782.626 us; speedup 1.0000x reference)
//
#include <hip/hip_runtime.h>
#include <hip/hip_fp16.h>
#include <float.h>
#include <math.h>

#define NEG_ATT 0.2f
#define NEG_ACT 0.01f
#define BK 512      // nodes per CSR bucket (bucket = dst >> 9)
#define NBMAX 128   // max buckets supported (N <= 65536)

__device__ __forceinline__ float lrelu(float v, float s) { return v >= 0.f ? v : s * v; }

struct __align__(16) H8 { __half2 a, b, c, d; };
struct __align__(8)  H4 { __half2 x, y; };

typedef _Float16 f16;
typedef f16 f16x8 __attribute__((ext_vector_type(8)));
typedef float f32x4 __attribute__((ext_vector_type(4)));

// ============ FRONT mega-kernel: encoder GEMM | W-prep | bucket histogram ============
// Feature layout from here on is HEAD-SLICED: ghs/hhs = [h][n][16] fp16 (32 B/node/head);
// alphas col-major [h][N] fp32. Role by blockIdx range.
__global__ __launch_bounds__(256) void k_front(
    const float* __restrict__ x, const float* __restrict__ W,
    const float* __restrict__ a_src, const float* __restrict__ a_dst,
    __half* __restrict__ ghs, float* __restrict__ as_h, float* __restrict__ ad_h,
    const float* __restrict__ hid_W, const float* __restrict__ hid_as,
    const float* __restrict__ hid_ad, __half* __restrict__ Wt,
    const int* __restrict__ ei, int* __restrict__ hist_part,
    int N, int E, int L, int nbEnc, int nbPrep) {
  __shared__ float sh[16 * 128 + 64 * 20];   // 13.3 KB, role-dependent reuse
  int tid = threadIdx.x;
  int bid = blockIdx.x;

  if (bid >= nbEnc + nbPrep) {
    // ---- histogram partials: 1024 edges/block, LDS-only, full overwrite ----
    int* lc = (int*)sh;
    if (tid < NBMAX) lc[tid] = 0;
    __syncthreads();
    int base = (bid - nbEnc - nbPrep) * 1024;
    #pragma unroll
    for (int j = 0; j < 4; ++j) {
      int e = base + j * 256 + tid;
      if (e < E) atomicAdd(&lc[ei[E + e] >> 9], 1);
    }
    __syncthreads();
    if (tid < NBMAX) hist_part[(size_t)(bid - nbEnc - nbPrep) * NBMAX + tid] = lc[tid];
    return;
  }
  if (bid >= nbEnc) {
    // ---- W prep for all hidden layers (rows 0-127 = W^T, 128-143 = W@[a_src|a_dst]) ----
    int idx = (bid - nbEnc) * 256 + tid;
    if (idx < L * 144 * 128) {
      int l = idx / (144 * 128);
      int rem = idx - l * 144 * 128;
      int r = rem >> 7, kk = rem & 127;
      const float* Wl = hid_W + (size_t)l * 128 * 128;
      float v;
      if (r < 128) {
        v = Wl[kk * 128 + r];
      } else {
        int hd = r - 128;
        const float* a = (hd < 8) ? (hid_as + (size_t)l * 128) : (hid_ad + (size_t)l * 128);
        int h2 = hd & 7;
        v = 0.f;
        #pragma unroll
        for (int c = 0; c < 16; ++c) v += Wl[kk * 128 + h2 * 16 + c] * a[h2 * 16 + c];
      }
      Wt[(size_t)l * 144 * 128 + r * 128 + kk] = __float2half(v);
    }
    return;
  }

  // ---- encoder GEMM (N x 16 @ 16 x 128), sliced outputs ----
  const int K = 16, KP = 20;
  float* Wl = sh;              // 16*128
  float* xl = sh + 16 * 128;   // 64*20
  int n0 = bid * 64;
  for (int i = tid * 4; i < (K << 6); i += 1024) {
    int row = i >> 4;
    int c = i & 15;
    float4 v = make_float4(0.f, 0.f, 0.f, 0.f);
    if (n0 + row < N) v = *(const float4*)(x + (size_t)(n0 + row) * K + c);
    *(float4*)(xl + row * KP + c) = v;
  }
  for (int i = tid * 4; i < 2048; i += 1024)
    *(float4*)(Wl + i) = *(const float4*)(W + i);
  __syncthreads();

  int ng = tid >> 4, jg = tid & 15;
  int jlo = jg * 4, jhi = 64 + jg * 4;
  float alo[4][4] = {}, ahi[4][4] = {};
  #pragma unroll 4
  for (int kk = 0; kk < K; ++kk) {
    const float4 wlo = *(const float4*)(Wl + (kk << 7) + jlo);
    const float4 whi = *(const float4*)(Wl + (kk << 7) + jhi);
    const float* xr = xl + (ng * 4) * KP + kk;
    #pragma unroll
    for (int i = 0; i < 4; ++i) {
      float xv = xr[i * KP];
      alo[i][0] += xv * wlo.x; alo[i][1] += xv * wlo.y;
      alo[i][2] += xv * wlo.z; alo[i][3] += xv * wlo.w;
      ahi[i][0] += xv * whi.x; ahi[i][1] += xv * whi.y;
      ahi[i][2] += xv * whi.z; ahi[i][3] += xv * whi.w;
    }
  }

  int hlo = jg >> 2, hhi = 4 + (jg >> 2), off4 = (jg & 3) * 4;
  #pragma unroll
  for (int i = 0; i < 4; ++i) {
    int n = n0 + ng * 4 + i;
    if (n >= N) break;
    H4 plo = { __floats2half2_rn(alo[i][0], alo[i][1]), __floats2half2_rn(alo[i][2], alo[i][3]) };
    H4 phi = { __floats2half2_rn(ahi[i][0], ahi[i][1]), __floats2half2_rn(ahi[i][2], ahi[i][3]) };
    *(H4*)(ghs + ((size_t)hlo * N + n) * 16 + off4) = plo;
    *(H4*)(ghs + ((size_t)hhi * N + n) * 16 + off4) = phi;
    float ps_lo = 0.f, pd_lo = 0.f, ps_hi = 0.f, pd_hi = 0.f;
    #pragma unroll
    for (int t = 0; t < 4; ++t) {
      ps_lo += alo[i][t] * a_src[hlo * 16 + off4 + t];
      pd_lo += alo[i][t] * a_dst[hlo * 16 + off4 + t];
      ps_hi += ahi[i][t] * a_src[hhi * 16 + off4 + t];
      pd_hi += ahi[i][t] * a_dst[hhi * 16 + off4 + t];
    }
    ps_lo += __shfl_xor(ps_lo, 1); ps_lo += __shfl_xor(ps_lo, 2);
    pd_lo += __shfl_xor(pd_lo, 1); pd_lo += __shfl_xor(pd_lo, 2);
    ps_hi += __shfl_xor(ps_hi, 1); ps_hi += __shfl_xor(ps_hi, 2);
    pd_hi += __shfl_xor(pd_hi, 1); pd_hi += __shfl_xor(pd_hi, 2);
    if ((jg & 3) == 0) {
      as_h[(size_t)hlo * N + n] = ps_lo; ad_h[(size_t)hlo * N + n] = pd_lo;
      as_h[(size_t)hhi * N + n] = ps_hi; ad_h[(size_t)hhi * N + n] = pd_hi;
    }
  }
}

// ======== bucket scan: reduce histogram partials, then exclusive scans ========
__global__ __launch_bounds__(1024) void k_bscan2(
    const int* __restrict__ hist_part, int nbHist,
    int* pair_st, int* bucket_st, int* pair_cur, int N, int NB) {
  __shared__ int part[1024];
  __shared__ int t1[128], t2[128];
  int tid = threadIdx.x;
  int colp = tid & 127, rg = tid >> 7;   // 8 row-groups
  int s = 0;
  for (int r = rg; r < nbHist; r += 8) s += hist_part[(size_t)r * NBMAX + colp];
  part[tid] = s;
  __syncthreads();
  int c = 0, nodesb = 0;
  if (tid < 128) {
    #pragma unroll
    for (int j = 0; j < 8; ++j) c += part[j * 128 + tid];
    if (tid < NB) {
      int base = tid * BK;
      nodesb = (N - base < BK) ? (N - base) : BK;
    }
    t1[tid] = c;
    t2[tid] = c + nodesb;
  }
  __syncthreads();
  for (int off = 1; off < 128; off <<= 1) {
    int a = 0, b = 0;
    if (tid < 128 && tid >= off) { a = t1[tid - off]; b = t2[tid - off]; }
    __syncthreads();
    if (tid < 128) { t1[tid] += a; t2[tid] += b; }
    __syncthreads();
  }
  if (tid < NB) {
    int ps = t1[tid] - c, bs = t2[tid] - (c + nodesb);
    pair_st[tid] = ps; pair_cur[tid] = ps; bucket_st[tid] = bs;
  }
  if (tid == 127) { pair_st[NB] = t1[127]; bucket_st[NB] = t2[127]; }
}

// append packed (src | local_dst<<17) into bucket regions
__global__ __launch_bounds__(1024) void k_bappend(const int* __restrict__ ei,
                                                  int* __restrict__ pair_cur,
                                                  int* __restrict__ pairs, int E, int NB) {
  __shared__ int lc[NBMAX], lb[NBMAX];
  int tid = threadIdx.x;
  if (tid < NB) lc[tid] = 0;
  __syncthreads();
  int e = blockIdx.x * 1024 + tid;
  int b = 0, r = 0, s = 0, d = 0;
  bool valid = e < E;
  if (valid) {
    s = ei[e]; d = ei[E + e]; b = d >> 9;
    r = atomicAdd(&lc[b], 1);
  }
  __syncthreads();
  if (tid < NB && lc[tid]) lb[tid] = atomicAdd(&pair_cur[tid], lc[tid]);
  __syncthreads();
  if (valid) pairs[lb[b] + r] = s | ((d & (BK - 1)) << 17);
}

__global__ __launch_bounds__(1024) void k_bbuild(const int* __restrict__ pairs,
    const int* __restrict__ pair_start, const int* __restrict__ bucket_start,
    int* __restrict__ row_ptr, int* __restrict__ colb, int N, int NB) {
  __shared__ int deg[BK], tmp[1024], cur[BK];
  int b = blockIdx.x, tid = threadIdx.x;
  int base = b * BK;
  int nodesb = (N - base < BK) ? (N - base) : BK;
  if (tid < BK) deg[tid] = (tid < nodesb) ? 1 : 0;  // self loop
  __syncthreads();
  int p0 = pair_start[b], p1 = pair_start[b + 1];
  for (int p = p0 + tid; p < p1; p += 1024)
    atomicAdd(&deg[pairs[p] >> 17], 1);
  __syncthreads();
  int v = (tid < BK) ? deg[tid] : 0;
  tmp[tid] = v;
  __syncthreads();
  for (int off = 1; off < 1024; off <<= 1) {
    int t = (tid >= off) ? tmp[tid - off] : 0;
    __syncthreads();
    tmp[tid] += t;
    __syncthreads();
  }
  int bs = bucket_start[b];
  if (tid < nodesb) {
    int ex = tmp[tid] - v;
    row_ptr[base + tid] = bs + ex;
    colb[bs + ex] = base + tid;  // self loop at segment head
    cur[tid] = ex + 1;
  }
  if (b == 0 && tid == 0) row_ptr[N] = bucket_start[NB];
  __syncthreads();
  for (int p = p0 + tid; p < p1; p += 1024) {
    int pr = pairs[p];
    int r = atomicAdd(&cur[pr >> 17], 1);
    colb[bs + r] = pr & 0x1FFFF;
  }
}

// ---------------- hidden GEMM via MFMA fp16 (N x 128 @ 128 x 144), sliced I/O ----------------
__global__ __launch_bounds__(256) void k_gemm_hid_mfma(
    const __half* __restrict__ hhs, const __half* __restrict__ Wt_g,
    __half* __restrict__ ghs, float* __restrict__ as_h, float* __restrict__ ad_h,
    int N) {
  __shared__ __half xh[64][136];
  __shared__ __half wt[144][136];
  int tid = threadIdx.x;
  int n0 = blockIdx.x * 64;

  // A tile from sliced layout: i -> slice hs = i>>7; chunk = i&127: row = chunk>>1, half = chunk&1
  for (int i = tid; i < 1024; i += 256) {
    int hs = i >> 7, chunk = i & 127;
    int row = chunk >> 1, hf = chunk & 1;
    float4 v = make_float4(0.f, 0.f, 0.f, 0.f);
    int node = n0 + row;
    if (node < N) v = *(const float4*)(hhs + ((size_t)hs * N + node) * 16 + hf * 8);
    *(float4*)(&xh[row][hs * 16 + hf * 8]) = v;
  }
  for (int i = tid; i < 2304; i += 256) {      // Wt: 144 x 128 halves
    int row = i >> 4, c8 = (i & 15) * 8;
    float4 v = *(const float4*)(Wt_g + (size_t)row * 128 + c8);
    *(float4*)(&wt[row][c8]) = v;
  }
  __syncthreads();

  int wave = tid >> 6, lane = tid & 63;
  int m = lane & 15, quad = lane >> 4;
  f32x4 acc[9] = {};
  #pragma unroll
  for (int kb = 0; kb < 128; kb += 32) {
    f16x8 a = *(const f16x8*)(&xh[wave * 16 + m][kb + quad * 8]);
    #pragma unroll
    for (int t = 0; t < 9; ++t) {
      f16x8 b = *(const f16x8*)(&wt[t * 16 + m][kb + quad * 8]);
      acc[t] = __builtin_amdgcn_mfma_f32_16x16x32_f16(a, b, acc[t], 0, 0, 0);
    }
  }

  // epilogue: tile t (= head) -> ghs slice t; tile 8 -> alphas col-major [h][N]
  #pragma unroll
  for (int r = 0; r < 4; ++r) {
    int node = n0 + wave * 16 + quad * 4 + r;
    if (node >= N) continue;
    #pragma unroll
    for (int t = 0; t < 8; ++t)
      ghs[((size_t)t * N + node) * 16 + m] = __float2half(acc[t][r]);
    float v = acc[8][r];
    if (m < 8) as_h[(size_t)m * N + node] = v;
    else       ad_h[(size_t)(m - 8) * N + node] = v;
  }
}

// ---------------- aggregation v9: head-sliced, 16 edges/instr, single pass ----------------
// blockIdx&7 = head h -> round-robin XCD pinning: per-XCD resident set = ghs
// slice (N x 32 B = 1.6 MB) + as/ad slices (0.4 MB) < 4 MB L2. col/row_ptr
// streamed non-temporally (x8 redundant read, cheap). One wave per node; lane
// = (eg = lane>>2 edge slot, cl = lane&3 channel quad). Per iter: 16 edges,
// each lane 1 H4 (8 B) gather + exp; den reduced over eg only (xor 4..32
// leaves cl groups intact, so each cl quad keeps the full denominator).
__global__ __launch_bounds__(256) void k_agg_slice(
    const int* __restrict__ row_ptr, const int* __restrict__ col,
    const float* __restrict__ as_h, const float* __restrict__ ad_h,
    const __half* __restrict__ ghs, const float* __restrict__ bias,
    __half* __restrict__ hhs, int N, int act) {
  int h = blockIdx.x & 7;
  int nb = blockIdx.x >> 3;
  int wv = threadIdx.x >> 6, lane = threadIdx.x & 63;
  int n = nb * 4 + wv;
  bool active = n < N;
  int nc = active ? n : 0;
  int s0 = row_ptr[nc];
  int s1 = active ? row_ptr[nc + 1] : s0;

  int eg = lane >> 2, cl = lane & 3;
  const float* ash = as_h + (size_t)h * N;
  float adv = ad_h[(size_t)h * N + nc];
  const __half* gb = ghs + (size_t)h * N * 16 + cl * 4;

  float den = 0.f, t0 = 0.f, t1 = 0.f, t2 = 0.f, t3 = 0.f;
  for (int b = s0; b < s1; b += 16) {
    int e = b + eg;
    if (e < s1) {
      int s = __builtin_nontemporal_load(col + e);
      float aa = ash[s];
      H4 hv = *(const H4*)(gb + (size_t)s * 16);
      float w = __expf(lrelu(aa + adv, NEG_ATT));
      den += w;
      float2 f0 = __half22float2(hv.x), f1 = __half22float2(hv.y);
      t0 += w * f0.x; t1 += w * f0.y; t2 += w * f1.x; t3 += w * f1.y;
    }
  }
  // reduce over edge slots only (xor masks 4,8,16,32 keep cl groups separate)
  den += __shfl_xor(den, 4); den += __shfl_xor(den, 8);
  den += __shfl_xor(den, 16); den += __shfl_xor(den, 32);
  t0 += __shfl_xor(t0, 4); t0 += __shfl_xor(t0, 8); t0 += __shfl_xor(t0, 16); t0 += __shfl_xor(t0, 32);
  t1 += __shfl_xor(t1, 4); t1 += __shfl_xor(t1, 8); t1 += __shfl_xor(t1, 16); t1 += __shfl_xor(t1, 32);
  t2 += __shfl_xor(t2, 4); t2 += __shfl_xor(t2, 8); t2 += __shfl_xor(t2, 16); t2 += __shfl_xor(t2, 32);
  t3 += __shfl_xor(t3, 4); t3 += __shfl_xor(t3, 8); t3 += __shfl_xor(t3, 16); t3 += __shfl_xor(t3, 32);

  if (active && eg == 0) {
    float inv = 1.f / den;
    int c0 = h * 16 + cl * 4;
    const float4 bv = *(const float4*)(bias + c0);
    float o0 = t0 * inv + bv.x, o1 = t1 * inv + bv.y;
    float o2 = t2 * inv + bv.z, o3 = t3 * inv + bv.w;
    if (act) {
      o0 = lrelu(o0, NEG_ACT); o1 = lrelu(o1, NEG_ACT);
      o2 = lrelu(o2, NEG_ACT); o3 = lrelu(o3, NEG_ACT);
    }
    H4 pk = { __floats2half2_rn(o0, o1), __floats2half2_rn(o2, o3) };
    *(H4*)(hhs + ((size_t)h * N + n) * 16 + cl * 4) = pk;
  }
}

// ---------------- decoder GEMM 128->3 (sliced fp16 in), pack (h0,h1,h2,alpha_src) ----------------
__global__ __launch_bounds__(256) void k_dec_gemm(
    const __half* __restrict__ hhs, const float* __restrict__ Wd,
    const float* __restrict__ asd, const float* __restrict__ add,
    float4* __restrict__ g4, float* __restrict__ adn, int N) {
  __shared__ float Wl[384];
  int tid = threadIdx.x;
  for (int i = tid; i < 384; i += 256) Wl[i] = Wd[i];
  __syncthreads();
  int n = blockIdx.x * 256 + tid;
  if (n >= N) return;
  float a0 = 0.f, a1 = 0.f, a2 = 0.f;
  #pragma unroll
  for (int h = 0; h < 8; ++h) {
    #pragma unroll
    for (int hf = 0; hf < 2; ++hf) {
      H8 hv = *(const H8*)(hhs + ((size_t)h * N + n) * 16 + hf * 8);
      int kbase = h * 16 + hf * 8;
      float f[8];
      float2 p;
      p = __half22float2(hv.a); f[0] = p.x; f[1] = p.y;
      p = __half22float2(hv.b); f[2] = p.x; f[3] = p.y;
      p = __half22float2(hv.c); f[4] = p.x; f[5] = p.y;
      p = __half22float2(hv.d); f[6] = p.x; f[7] = p.y;
      #pragma unroll
      for (int i = 0; i < 8; ++i) {
        a0 += f[i] * Wl[(kbase + i) * 3];
        a1 += f[i] * Wl[(kbase + i) * 3 + 1];
        a2 += f[i] * Wl[(kbase + i) * 3 + 2];
      }
    }
  }
  float as_n = a0 * asd[0] + a1 * asd[1] + a2 * asd[2];
  g4[n] = make_float4(a0, a1, a2, as_n);
  adn[n] = a0 * add[0] + a1 * add[1] + a2 * add[2];
}

// ---------------- decoder aggregation, H=1 C=3, direct exp (no max) ----------------
__global__ __launch_bounds__(256) void k_dec_agg(
    const int* __restrict__ row_ptr, const int* __restrict__ col,
    const float* __restrict__ ad, const float4* __restrict__ g4,
    const float* __restrict__ b, float* __restrict__ out, int N) {
  int n = blockIdx.x * blockDim.x + threadIdx.x;
  if (n >= N) return;
  int s0 = row_ptr[n], s1 = row_ptr[n + 1];
  float adv = ad[n];
  float den = 0.f, A0 = 0.f, A1 = 0.f, A2 = 0.f;
  int k = s0;
  for (; k + 4 <= s1; k += 4) {
    int sa = col[k], sb = col[k + 1], sc = col[k + 2], sd = col[k + 3];
    float4 v0 = g4[sa], v1 = g4[sb], v2 = g4[sc], v3 = g4[sd];
    float w0 = __expf(lrelu(v0.w + adv, NEG_ATT));
    float w1 = __expf(lrelu(v1.w + adv, NEG_ATT));
    float w2 = __expf(lrelu(v2.w + adv, NEG_ATT));
    float w3 = __expf(lrelu(v3.w + adv, NEG_ATT));
    den += w0 + w1 + w2 + w3;
    A0 += w0 * v0.x + w1 * v1.x + w2 * v2.x + w3 * v3.x;
    A1 += w0 * v0.y + w1 * v1.y + w2 * v2.y + w3 * v3.y;
    A2 += w0 * v0.z + w1 * v1.z + w2 * v2.z + w3 * v3.z;
  }
  for (; k < s1; ++k) {
    float4 v = g4[col[k]];
    float w = __expf(lrelu(v.w + adv, NEG_ATT));
    den += w;
    A0 += w * v.x; A1 += w * v.y; A2 += w * v.z;
  }
  float inv = 1.f / den;
  out[(size_t)n * 3]     = A0 * inv + b[0];
  out[(size_t)n * 3 + 1] = A1 * inv + b[1];
  out[(size_t)n * 3 + 2] = A2 * inv + b[2];
}

// ---------------- host ----------------
extern "C" void kernel_launch(void* const* d_in, const int* in_sizes, int n_in,
                              void* d_out, int out_size, void* d_ws, size_t ws_size,
                              hipStream_t stream) {
  const float* x      = (const float*)d_in[0];
  const int*   ei     = (const int*)d_in[1];
  const float* enc_W  = (const float*)d_in[2];
  const float* enc_as = (const float*)d_in[3];
  const float* enc_ad = (const float*)d_in[4];
  const float* enc_b  = (const float*)d_in[5];
  const float* hid_W  = (const float*)d_in[6];
  const float* hid_as = (const float*)d_in[7];
  const float* hid_ad = (const float*)d_in[8];
  const float* hid_b  = (const float*)d_in[9];
  const float* dec_W  = (const float*)d_in[10];
  const float* dec_as = (const float*)d_in[11];
  const float* dec_ad = (const float*)d_in[12];
  const float* dec_b  = (const float*)d_in[13];

  const int N = in_sizes[0] / 16;
  const int E = in_sizes[1] / 2;
  const int L = in_sizes[6] / (128 * 128);
  const int NB = (N + BK - 1) / BK;  // assumed <= NBMAX (N <= 65536)

  // workspace carve-out
  char* wbase = (char*)d_ws;
  size_t woff = 0;
  auto walloc = [&](size_t bytes, size_t align) -> void* {
    woff = (woff + align - 1) & ~(align - 1);
    void* p = wbase + woff;
    woff += bytes;
    return p;
  };
  const int nbEnc  = (N + 63) / 64;
  const int nbPrep = (L * 144 * 128 + 255) / 256;
  const int nbHist = (E + 1023) / 1024;

  __half* ghs       = (__half*)walloc((size_t)N * 128 * 2, 16);  // pre-agg, sliced [h][n][16]
  __half* hhs       = (__half*)walloc((size_t)N * 128 * 2, 16);  // post-agg, sliced
  float*  as_h      = (float*)walloc((size_t)N * 8 * 4, 16);     // col-major [h][N]
  float*  ad_h      = (float*)walloc((size_t)N * 8 * 4, 16);
  float4* g4        = (float4*)walloc((size_t)N * 16, 16);
  float*  adn       = (float*)walloc((size_t)N * 4, 16);
  __half* Wt_g      = (__half*)walloc((size_t)3 * 144 * 128 * 2, 16);
  int*    row_ptr   = (int*)walloc((size_t)(N + 1) * 4, 4);
  int*    colb      = (int*)walloc((size_t)(E + N) * 4, 4);
  int*    pairs     = (int*)walloc((size_t)E * 4, 4);
  int*    hist_part = (int*)walloc((size_t)nbHist * NBMAX * 4, 4);
  int*    pair_st   = (int*)walloc((NBMAX + 1) * 4, 4);
  int*    bucket_st = (int*)walloc((NBMAX + 1) * 4, 4);
  int*    pair_cur  = (int*)walloc((NBMAX + 1) * 4, 4);

  const dim3 b256(256);
  const dim3 gFront(nbEnc + nbPrep + nbHist);
  const dim3 gGemm(nbEnc);
  const dim3 gAgg(((N + 3) / 4) * 8);
  const dim3 gNode((N + 255) / 256);

  // 1) front: encoder + W-prep + histogram partials (one launch)
  k_front<<<gFront, b256, 0, stream>>>(x, enc_W, enc_as, enc_ad, ghs, as_h, ad_h,
                                       hid_W, hid_as, hid_ad, Wt_g, ei, hist_part,
                                       N, E, L, nbEnc, nbPrep);
  // 2) CSR: scan, append, build
  k_bscan2<<<dim3(1), dim3(1024), 0, stream>>>(hist_part, nbHist, pair_st, bucket_st,
                                               pair_cur, N, NB);
  k_bappend<<<dim3(nbHist), dim3(1024), 0, stream>>>(ei, pair_cur, pairs, E, NB);
  k_bbuild<<<dim3(NB), dim3(1024), 0, stream>>>(pairs, pair_st, bucket_st, row_ptr, colb, N, NB);

  // 3) encoder agg (act=1)
  k_agg_slice<<<gAgg, b256, 0, stream>>>(row_ptr, colb, as_h, ad_h, ghs, enc_b, hhs, N, 1);

  // 4) hidden layers
  for (int l = 0; l < L; ++l) {
    k_gemm_hid_mfma<<<gGemm, b256, 0, stream>>>(hhs, Wt_g + (size_t)l * 144 * 128,
                                                ghs, as_h, ad_h, N);
    k_agg_slice<<<gAgg, b256, 0, stream>>>(row_ptr, colb, as_h, ad_h, ghs,
                                           hid_b + (size_t)l * 128, hhs, N, 0);
  }

  // 5) decoder
  k_dec_gemm<<<gNode, b256, 0, stream>>>(hhs, dec_W, dec_as, dec_ad, g4, adn, N);
  k_dec_agg<<<gNode, b256, 0, stream>>>(row_ptr, colb, adn, g4, dec_b,
                                        (float*)d_out, N);
}

// Round 12
// 366.154 us; speedup vs baseline: 2.1374x; 2.1374x over previous
//
#include <hip/hip_runtime.h>
#include <hip/hip_fp16.h>
#include <float.h>
#include <math.h>

#define NEG_ATT 0.2f
#define NEG_ACT 0.01f
#define BK 512      // nodes per CSR bucket (bucket = dst >> 9)
#define NBMAX 128   // max buckets supported (N <= 65536)

__device__ __forceinline__ float lrelu(float v, float s) { return v >= 0.f ? v : s * v; }

struct __align__(16) H8 { __half2 a, b, c, d; };
struct __align__(8)  H4 { __half2 x, y; };

typedef _Float16 f16;
typedef f16 f16x8 __attribute__((ext_vector_type(8)));
typedef float f32x4 __attribute__((ext_vector_type(4)));

// ============ FRONT mega-kernel: encoder GEMM | W-prep | bucket histogram ============
__global__ __launch_bounds__(256) void k_front(
    const float* __restrict__ x, const float* __restrict__ W,
    const float* __restrict__ a_src, const float* __restrict__ a_dst,
    __half* __restrict__ gh, float* __restrict__ as_out, float* __restrict__ ad_out,
    const float* __restrict__ hid_W, const float* __restrict__ hid_as,
    const float* __restrict__ hid_ad, __half* __restrict__ Wt,
    const int* __restrict__ ei, int* __restrict__ hist_part,
    int N, int E, int L, int nbEnc, int nbPrep) {
  __shared__ float sh[16 * 128 + 64 * 20];   // 13.3 KB, role-dependent reuse
  int tid = threadIdx.x;
  int bid = blockIdx.x;

  if (bid >= nbEnc + nbPrep) {
    // ---- histogram partials: 1024 edges/block, LDS-only, full overwrite ----
    int* lc = (int*)sh;
    if (tid < NBMAX) lc[tid] = 0;
    __syncthreads();
    int base = (bid - nbEnc - nbPrep) * 1024;
    #pragma unroll
    for (int j = 0; j < 4; ++j) {
      int e = base + j * 256 + tid;
      if (e < E) atomicAdd(&lc[ei[E + e] >> 9], 1);
    }
    __syncthreads();
    if (tid < NBMAX) hist_part[(size_t)(bid - nbEnc - nbPrep) * NBMAX + tid] = lc[tid];
    return;
  }
  if (bid >= nbEnc) {
    // ---- W prep for all hidden layers (rows 0-127 = W^T, 128-143 = W@[a_src|a_dst]) ----
    int idx = (bid - nbEnc) * 256 + tid;
    if (idx < L * 144 * 128) {
      int l = idx / (144 * 128);
      int rem = idx - l * 144 * 128;
      int r = rem >> 7, kk = rem & 127;
      const float* Wl = hid_W + (size_t)l * 128 * 128;
      float v;
      if (r < 128) {
        v = Wl[kk * 128 + r];
      } else {
        int hd = r - 128;
        const float* a = (hd < 8) ? (hid_as + (size_t)l * 128) : (hid_ad + (size_t)l * 128);
        int h2 = hd & 7;
        v = 0.f;
        #pragma unroll
        for (int c = 0; c < 16; ++c) v += Wl[kk * 128 + h2 * 16 + c] * a[h2 * 16 + c];
      }
      Wt[(size_t)l * 144 * 128 + r * 128 + kk] = __float2half(v);
    }
    return;
  }

  // ---- encoder GEMM (N x 16 @ 16 x 128) ----
  const int K = 16, KP = 20;
  float* Wl = sh;              // 16*128
  float* xl = sh + 16 * 128;   // 64*20
  int n0 = bid * 64;
  for (int i = tid * 4; i < (K << 6); i += 1024) {
    int row = i >> 4;
    int c = i & 15;
    float4 v = make_float4(0.f, 0.f, 0.f, 0.f);
    if (n0 + row < N) v = *(const float4*)(x + (size_t)(n0 + row) * K + c);
    *(float4*)(xl + row * KP + c) = v;
  }
  for (int i = tid * 4; i < 2048; i += 1024)
    *(float4*)(Wl + i) = *(const float4*)(W + i);
  __syncthreads();

  int ng = tid >> 4, jg = tid & 15;
  int jlo = jg * 4, jhi = 64 + jg * 4;
  float alo[4][4] = {}, ahi[4][4] = {};
  #pragma unroll 4
  for (int kk = 0; kk < K; ++kk) {
    const float4 wlo = *(const float4*)(Wl + (kk << 7) + jlo);
    const float4 whi = *(const float4*)(Wl + (kk << 7) + jhi);
    const float* xr = xl + (ng * 4) * KP + kk;
    #pragma unroll
    for (int i = 0; i < 4; ++i) {
      float xv = xr[i * KP];
      alo[i][0] += xv * wlo.x; alo[i][1] += xv * wlo.y;
      alo[i][2] += xv * wlo.z; alo[i][3] += xv * wlo.w;
      ahi[i][0] += xv * whi.x; ahi[i][1] += xv * whi.y;
      ahi[i][2] += xv * whi.z; ahi[i][3] += xv * whi.w;
    }
  }

  int hlo = jg >> 2, hhi = 4 + (jg >> 2), off4 = (jg & 3) * 4;
  #pragma unroll
  for (int i = 0; i < 4; ++i) {
    int n = n0 + ng * 4 + i;
    if (n >= N) break;
    H4 plo = { __floats2half2_rn(alo[i][0], alo[i][1]), __floats2half2_rn(alo[i][2], alo[i][3]) };
    H4 phi = { __floats2half2_rn(ahi[i][0], ahi[i][1]), __floats2half2_rn(ahi[i][2], ahi[i][3]) };
    *(H4*)(gh + (size_t)n * 128 + jlo) = plo;
    *(H4*)(gh + (size_t)n * 128 + jhi) = phi;
    float ps_lo = 0.f, pd_lo = 0.f, ps_hi = 0.f, pd_hi = 0.f;
    #pragma unroll
    for (int t = 0; t < 4; ++t) {
      ps_lo += alo[i][t] * a_src[hlo * 16 + off4 + t];
      pd_lo += alo[i][t] * a_dst[hlo * 16 + off4 + t];
      ps_hi += ahi[i][t] * a_src[hhi * 16 + off4 + t];
      pd_hi += ahi[i][t] * a_dst[hhi * 16 + off4 + t];
    }
    ps_lo += __shfl_xor(ps_lo, 1); ps_lo += __shfl_xor(ps_lo, 2);
    pd_lo += __shfl_xor(pd_lo, 1); pd_lo += __shfl_xor(pd_lo, 2);
    ps_hi += __shfl_xor(ps_hi, 1); ps_hi += __shfl_xor(ps_hi, 2);
    pd_hi += __shfl_xor(pd_hi, 1); pd_hi += __shfl_xor(pd_hi, 2);
    if ((jg & 3) == 0) {
      as_out[n * 8 + hlo] = ps_lo; ad_out[n * 8 + hlo] = pd_lo;
      as_out[n * 8 + hhi] = ps_hi; ad_out[n * 8 + hhi] = pd_hi;
    }
  }
}

// ======== bucket scan: reduce histogram partials, then exclusive scans ========
__global__ __launch_bounds__(1024) void k_bscan2(
    const int* __restrict__ hist_part, int nbHist,
    int* pair_st, int* bucket_st, int* pair_cur, int N, int NB) {
  __shared__ int part[1024];
  __shared__ int t1[128], t2[128];
  int tid = threadIdx.x;
  int colp = tid & 127, rg = tid >> 7;   // 8 row-groups
  int s = 0;
  for (int r = rg; r < nbHist; r += 8) s += hist_part[(size_t)r * NBMAX + colp];
  part[tid] = s;
  __syncthreads();
  int c = 0, nodesb = 0;
  if (tid < 128) {
    #pragma unroll
    for (int j = 0; j < 8; ++j) c += part[j * 128 + tid];
    if (tid < NB) {
      int base = tid * BK;
      nodesb = (N - base < BK) ? (N - base) : BK;
    }
    t1[tid] = c;
    t2[tid] = c + nodesb;
  }
  __syncthreads();
  for (int off = 1; off < 128; off <<= 1) {
    int a = 0, b = 0;
    if (tid < 128 && tid >= off) { a = t1[tid - off]; b = t2[tid - off]; }
    __syncthreads();
    if (tid < 128) { t1[tid] += a; t2[tid] += b; }
    __syncthreads();
  }
  if (tid < NB) {
    int ps = t1[tid] - c, bs = t2[tid] - (c + nodesb);
    pair_st[tid] = ps; pair_cur[tid] = ps; bucket_st[tid] = bs;
  }
  if (tid == 127) { pair_st[NB] = t1[127]; bucket_st[NB] = t2[127]; }
}

// append packed (src | local_dst<<17) into bucket regions
__global__ __launch_bounds__(1024) void k_bappend(const int* __restrict__ ei,
                                                  int* __restrict__ pair_cur,
                                                  int* __restrict__ pairs, int E, int NB) {
  __shared__ int lc[NBMAX], lb[NBMAX];
  int tid = threadIdx.x;
  if (tid < NB) lc[tid] = 0;
  __syncthreads();
  int e = blockIdx.x * 1024 + tid;
  int b = 0, r = 0, s = 0, d = 0;
  bool valid = e < E;
  if (valid) {
    s = ei[e]; d = ei[E + e]; b = d >> 9;
    r = atomicAdd(&lc[b], 1);
  }
  __syncthreads();
  if (tid < NB && lc[tid]) lb[tid] = atomicAdd(&pair_cur[tid], lc[tid]);
  __syncthreads();
  if (valid) pairs[lb[b] + r] = s | ((d & (BK - 1)) << 17);
}

__global__ __launch_bounds__(1024) void k_bbuild(const int* __restrict__ pairs,
    const int* __restrict__ pair_start, const int* __restrict__ bucket_start,
    int* __restrict__ row_ptr, int* __restrict__ colb, int N, int NB) {
  __shared__ int deg[BK], tmp[1024], cur[BK];
  int b = blockIdx.x, tid = threadIdx.x;
  int base = b * BK;
  int nodesb = (N - base < BK) ? (N - base) : BK;
  if (tid < BK) deg[tid] = (tid < nodesb) ? 1 : 0;  // self loop
  __syncthreads();
  int p0 = pair_start[b], p1 = pair_start[b + 1];
  for (int p = p0 + tid; p < p1; p += 1024)
    atomicAdd(&deg[pairs[p] >> 17], 1);
  __syncthreads();
  int v = (tid < BK) ? deg[tid] : 0;
  tmp[tid] = v;
  __syncthreads();
  for (int off = 1; off < 1024; off <<= 1) {
    int t = (tid >= off) ? tmp[tid - off] : 0;
    __syncthreads();
    tmp[tid] += t;
    __syncthreads();
  }
  int bs = bucket_start[b];
  if (tid < nodesb) {
    int ex = tmp[tid] - v;
    row_ptr[base + tid] = bs + ex;
    colb[bs + ex] = base + tid;  // self loop at segment head
    cur[tid] = ex + 1;
  }
  if (b == 0 && tid == 0) row_ptr[N] = bucket_start[NB];
  __syncthreads();
  for (int p = p0 + tid; p < p1; p += 1024) {
    int pr = pairs[p];
    int r = atomicAdd(&cur[pr >> 17], 1);
    colb[bs + r] = pr & 0x1FFFF;
  }
}

// ---------------- hidden GEMM via MFMA fp16 (N x 128 @ 128 x 144) ----------------
__global__ __launch_bounds__(256) void k_gemm_hid_mfma(
    const __half* __restrict__ xh_g, const __half* __restrict__ Wt_g,
    __half* __restrict__ gh, float* __restrict__ as_out, float* __restrict__ ad_out,
    int N) {
  __shared__ __half xh[64][136];
  __shared__ __half wt[144][136];
  int tid = threadIdx.x;
  int n0 = blockIdx.x * 64;

  for (int i = tid; i < 1024; i += 256) {      // x tile: 64 x 128 halves
    int row = i >> 4, c8 = (i & 15) * 8;
    float4 v = make_float4(0.f, 0.f, 0.f, 0.f);
    if (n0 + row < N) v = *(const float4*)(xh_g + (size_t)(n0 + row) * 128 + c8);
    *(float4*)(&xh[row][c8]) = v;
  }
  for (int i = tid; i < 2304; i += 256) {      // Wt: 144 x 128 halves
    int row = i >> 4, c8 = (i & 15) * 8;
    float4 v = *(const float4*)(Wt_g + (size_t)row * 128 + c8);
    *(float4*)(&wt[row][c8]) = v;
  }
  __syncthreads();

  int wave = tid >> 6, lane = tid & 63;
  int m = lane & 15, quad = lane >> 4;
  f32x4 acc[9] = {};
  #pragma unroll
  for (int kb = 0; kb < 128; kb += 32) {
    f16x8 a = *(const f16x8*)(&xh[wave * 16 + m][kb + quad * 8]);
    #pragma unroll
    for (int t = 0; t < 9; ++t) {
      f16x8 b = *(const f16x8*)(&wt[t * 16 + m][kb + quad * 8]);
      acc[t] = __builtin_amdgcn_mfma_f32_16x16x32_f16(a, b, acc[t], 0, 0, 0);
    }
  }

  // epilogue: tiles 0-7 -> gh fp16; tile 8 -> alphas fp32
  #pragma unroll
  for (int r = 0; r < 4; ++r) {
    int node = n0 + wave * 16 + quad * 4 + r;
    if (node >= N) continue;
    #pragma unroll
    for (int t = 0; t < 8; ++t)
      gh[(size_t)node * 128 + t * 16 + m] = __float2half(acc[t][r]);
    float v = acc[8][r];
    if (m < 8) as_out[node * 8 + m] = v;
    else       ad_out[node * 8 + (m - 8)] = v;
  }
}

// ---------------- aggregation v10: single-pass, fp16 packed numerator ----------------
// v7 structure (one wave/node, quarter-wave per edge, 4 edges/instr) with the
// numerator accumulated in __half2 via __hfma2 (4 pk-FMA per H8 instead of
// 4 pk-cvt + 8 fp32 FMA); den stays fp32. Partial sums per quarter are ~4-5
// terms of ~0.3 magnitude -> fp16 noise ~1e-4/layer after /den. col streamed
// non-temporally. dec==1: fused decoder GEMM epilogue (unchanged, fp32).
__global__ __launch_bounds__(256) void k_agg128(
    const int* __restrict__ row_ptr, const int* __restrict__ col,
    const float* __restrict__ as, const float* __restrict__ ad,
    const __half* __restrict__ gh, const float* __restrict__ bias,
    __half* __restrict__ out, int N, int act,
    int dec, const float* __restrict__ dWd, const float* __restrict__ dasd,
    const float* __restrict__ dadd, float4* __restrict__ g4, float* __restrict__ adn) {
  int wid = threadIdx.x >> 6;
  int lane = threadIdx.x & 63;
  int n = blockIdx.x * 4 + wid;
  bool active = n < N;
  int nc = active ? n : 0;
  int s0 = active ? row_ptr[nc] : 0;
  int s1 = active ? row_ptr[nc + 1] : 0;

  int q = lane >> 4, l16 = lane & 15;
  int c0 = l16 * 8, hq = l16 >> 1;
  float adq = ad[nc * 8 + hq];
  const __half* gq = gh + c0;
  const float* asq = as + hq;
  float den = 0.f;
  __half2 zero2 = __float2half2_rn(0.f);
  __half2 m0 = zero2, m1 = zero2, m2 = zero2, m3 = zero2;

  int b = s0;
  for (; b + 16 <= s1; b += 16) {   // 16 edges/wave iter; 4 H8 + 4 as in flight/lane
    int e0 = b + q, e1 = b + 4 + q, e2 = b + 8 + q, e3 = b + 12 + q;
    int sa = __builtin_nontemporal_load(col + e0);
    int sb = __builtin_nontemporal_load(col + e1);
    int sc = __builtin_nontemporal_load(col + e2);
    int sd = __builtin_nontemporal_load(col + e3);
    float aa = asq[sa * 8], ab = asq[sb * 8], ac = asq[sc * 8], ae = asq[sd * 8];
    H8 ha = *(const H8*)(gq + (size_t)sa * 128);
    H8 hb = *(const H8*)(gq + (size_t)sb * 128);
    H8 hc = *(const H8*)(gq + (size_t)sc * 128);
    H8 hd = *(const H8*)(gq + (size_t)sd * 128);
    float wa = __expf(lrelu(aa + adq, NEG_ATT));
    float wb = __expf(lrelu(ab + adq, NEG_ATT));
    float wc = __expf(lrelu(ac + adq, NEG_ATT));
    float wd = __expf(lrelu(ae + adq, NEG_ATT));
    den += wa + wb + wc + wd;
    __half2 wah = __float2half2_rn(wa), wbh = __float2half2_rn(wb);
    __half2 wch = __float2half2_rn(wc), wdh = __float2half2_rn(wd);
    m0 = __hfma2(wah, ha.a, m0); m1 = __hfma2(wah, ha.b, m1);
    m2 = __hfma2(wah, ha.c, m2); m3 = __hfma2(wah, ha.d, m3);
    m0 = __hfma2(wbh, hb.a, m0); m1 = __hfma2(wbh, hb.b, m1);
    m2 = __hfma2(wbh, hb.c, m2); m3 = __hfma2(wbh, hb.d, m3);
    m0 = __hfma2(wch, hc.a, m0); m1 = __hfma2(wch, hc.b, m1);
    m2 = __hfma2(wch, hc.c, m2); m3 = __hfma2(wch, hc.d, m3);
    m0 = __hfma2(wdh, hd.a, m0); m1 = __hfma2(wdh, hd.b, m1);
    m2 = __hfma2(wdh, hd.c, m2); m3 = __hfma2(wdh, hd.d, m3);
  }
  for (; b + 4 <= s1; b += 4) {     // 4 edges / wave iter
    int e0 = b + q;
    int sa = __builtin_nontemporal_load(col + e0);
    float aa = asq[sa * 8];
    H8 ha = *(const H8*)(gq + (size_t)sa * 128);
    float wa = __expf(lrelu(aa + adq, NEG_ATT));
    den += wa;
    __half2 wah = __float2half2_rn(wa);
    m0 = __hfma2(wah, ha.a, m0); m1 = __hfma2(wah, ha.b, m1);
    m2 = __hfma2(wah, ha.c, m2); m3 = __hfma2(wah, ha.d, m3);
  }
  if (b + q < s1) {                 // masked remainder (<4 edges)
    int e0 = b + q;
    int sa = __builtin_nontemporal_load(col + e0);
    float aa = asq[sa * 8];
    H8 ha = *(const H8*)(gq + (size_t)sa * 128);
    float wa = __expf(lrelu(aa + adq, NEG_ATT));
    den += wa;
    __half2 wah = __float2half2_rn(wa);
    m0 = __hfma2(wah, ha.a, m0); m1 = __hfma2(wah, ha.b, m1);
    m2 = __hfma2(wah, ha.c, m2); m3 = __hfma2(wah, ha.d, m3);
  }

  // convert packed partials to fp32, then reduce across quarters
  float2 f0 = __half22float2(m0), f1 = __half22float2(m1);
  float2 f2 = __half22float2(m2), f3 = __half22float2(m3);
  float t0 = f0.x, t1 = f0.y, t2 = f1.x, t3 = f1.y;
  float t4 = f2.x, t5 = f2.y, t6 = f3.x, t7 = f3.y;
  den += __shfl_xor(den, 16); den += __shfl_xor(den, 32);
  t0 += __shfl_xor(t0, 16); t0 += __shfl_xor(t0, 32);
  t1 += __shfl_xor(t1, 16); t1 += __shfl_xor(t1, 32);
  t2 += __shfl_xor(t2, 16); t2 += __shfl_xor(t2, 32);
  t3 += __shfl_xor(t3, 16); t3 += __shfl_xor(t3, 32);
  t4 += __shfl_xor(t4, 16); t4 += __shfl_xor(t4, 32);
  t5 += __shfl_xor(t5, 16); t5 += __shfl_xor(t5, 32);
  t6 += __shfl_xor(t6, 16); t6 += __shfl_xor(t6, 32);
  t7 += __shfl_xor(t7, 16); t7 += __shfl_xor(t7, 32);

  float inv = 1.f / den;
  const float4 b0 = *(const float4*)(bias + c0);
  const float4 b1 = *(const float4*)(bias + c0 + 4);
  float o0 = t0 * inv + b0.x, o1 = t1 * inv + b0.y;
  float o2 = t2 * inv + b0.z, o3 = t3 * inv + b0.w;
  float o4 = t4 * inv + b1.x, o5 = t5 * inv + b1.y;
  float o6 = t6 * inv + b1.z, o7 = t7 * inv + b1.w;
  if (act) {
    o0 = lrelu(o0, NEG_ACT); o1 = lrelu(o1, NEG_ACT);
    o2 = lrelu(o2, NEG_ACT); o3 = lrelu(o3, NEG_ACT);
    o4 = lrelu(o4, NEG_ACT); o5 = lrelu(o5, NEG_ACT);
    o6 = lrelu(o6, NEG_ACT); o7 = lrelu(o7, NEG_ACT);
  }
  if (!dec) {
    if (active && q == 0) {
      H8 pk = { __floats2half2_rn(o0, o1), __floats2half2_rn(o2, o3),
                __floats2half2_rn(o4, o5), __floats2half2_rn(o6, o7) };
      *(H8*)(out + (size_t)n * 128 + c0) = pk;
    }
  } else {
    // fused decoder GEMM: partial 8-col dot, reduce across the 16 q==0 lanes.
    float ov[8] = {o0, o1, o2, o3, o4, o5, o6, o7};
    float p0 = 0.f, p1 = 0.f, p2 = 0.f;
    #pragma unroll
    for (int i = 0; i < 8; ++i) {
      float wv0 = dWd[(c0 + i) * 3], wv1 = dWd[(c0 + i) * 3 + 1], wv2 = dWd[(c0 + i) * 3 + 2];
      p0 += ov[i] * wv0; p1 += ov[i] * wv1; p2 += ov[i] * wv2;
    }
    p0 += __shfl_xor(p0, 1); p0 += __shfl_xor(p0, 2); p0 += __shfl_xor(p0, 4); p0 += __shfl_xor(p0, 8);
    p1 += __shfl_xor(p1, 1); p1 += __shfl_xor(p1, 2); p1 += __shfl_xor(p1, 4); p1 += __shfl_xor(p1, 8);
    p2 += __shfl_xor(p2, 1); p2 += __shfl_xor(p2, 2); p2 += __shfl_xor(p2, 4); p2 += __shfl_xor(p2, 8);
    if (active && lane == 0) {
      float as_n = p0 * dasd[0] + p1 * dasd[1] + p2 * dasd[2];
      float ad_n = p0 * dadd[0] + p1 * dadd[1] + p2 * dadd[2];
      g4[n] = make_float4(p0, p1, p2, as_n);
      adn[n] = ad_n;
    }
  }
}

// ---------------- decoder aggregation, H=1 C=3, direct exp (no max) ----------------
__global__ __launch_bounds__(256) void k_dec_agg(
    const int* __restrict__ row_ptr, const int* __restrict__ col,
    const float* __restrict__ ad, const float4* __restrict__ g4,
    const float* __restrict__ b, float* __restrict__ out, int N) {
  int n = blockIdx.x * blockDim.x + threadIdx.x;
  if (n >= N) return;
  int s0 = row_ptr[n], s1 = row_ptr[n + 1];
  float adv = ad[n];
  float den = 0.f, A0 = 0.f, A1 = 0.f, A2 = 0.f;
  int k = s0;
  for (; k + 4 <= s1; k += 4) {
    int sa = col[k], sb = col[k + 1], sc = col[k + 2], sd = col[k + 3];
    float4 v0 = g4[sa], v1 = g4[sb], v2 = g4[sc], v3 = g4[sd];
    float w0 = __expf(lrelu(v0.w + adv, NEG_ATT));
    float w1 = __expf(lrelu(v1.w + adv, NEG_ATT));
    float w2 = __expf(lrelu(v2.w + adv, NEG_ATT));
    float w3 = __expf(lrelu(v3.w + adv, NEG_ATT));
    den += w0 + w1 + w2 + w3;
    A0 += w0 * v0.x + w1 * v1.x + w2 * v2.x + w3 * v3.x;
    A1 += w0 * v0.y + w1 * v1.y + w2 * v2.y + w3 * v3.y;
    A2 += w0 * v0.z + w1 * v1.z + w2 * v2.z + w3 * v3.z;
  }
  for (; k < s1; ++k) {
    float4 v = g4[col[k]];
    float w = __expf(lrelu(v.w + adv, NEG_ATT));
    den += w;
    A0 += w * v.x; A1 += w * v.y; A2 += w * v.z;
  }
  float inv = 1.f / den;
  out[(size_t)n * 3]     = A0 * inv + b[0];
  out[(size_t)n * 3 + 1] = A1 * inv + b[1];
  out[(size_t)n * 3 + 2] = A2 * inv + b[2];
}

// ---------------- host ----------------
extern "C" void kernel_launch(void* const* d_in, const int* in_sizes, int n_in,
                              void* d_out, int out_size, void* d_ws, size_t ws_size,
                              hipStream_t stream) {
  const float* x      = (const float*)d_in[0];
  const int*   ei     = (const int*)d_in[1];
  const float* enc_W  = (const float*)d_in[2];
  const float* enc_as = (const float*)d_in[3];
  const float* enc_ad = (const float*)d_in[4];
  const float* enc_b  = (const float*)d_in[5];
  const float* hid_W  = (const float*)d_in[6];
  const float* hid_as = (const float*)d_in[7];
  const float* hid_ad = (const float*)d_in[8];
  const float* hid_b  = (const float*)d_in[9];
  const float* dec_W  = (const float*)d_in[10];
  const float* dec_as = (const float*)d_in[11];
  const float* dec_ad = (const float*)d_in[12];
  const float* dec_b  = (const float*)d_in[13];

  const int N = in_sizes[0] / 16;
  const int E = in_sizes[1] / 2;
  const int L = in_sizes[6] / (128 * 128);
  const int NB = (N + BK - 1) / BK;  // assumed <= NBMAX (N <= 65536)

  // workspace carve-out
  char* wbase = (char*)d_ws;
  size_t woff = 0;
  auto walloc = [&](size_t bytes, size_t align) -> void* {
    woff = (woff + align - 1) & ~(align - 1);
    void* p = wbase + woff;
    woff += bytes;
    return p;
  };
  const int nbEnc  = (N + 63) / 64;
  const int nbPrep = (L * 144 * 128 + 255) / 256;
  const int nbHist = (E + 1023) / 1024;

  __half* gh        = (__half*)walloc((size_t)N * 128 * 2, 16);  // pre-agg features
  __half* hh        = (__half*)walloc((size_t)N * 128 * 2, 16);  // post-agg features
  float*  as_buf    = (float*)walloc((size_t)N * 8 * 4, 16);
  float*  ad_buf    = (float*)walloc((size_t)N * 8 * 4, 16);
  float4* g4        = (float4*)walloc((size_t)N * 16, 16);
  float*  adn       = (float*)walloc((size_t)N * 4, 16);
  __half* Wt_g      = (__half*)walloc((size_t)3 * 144 * 128 * 2, 16);
  int*    row_ptr   = (int*)walloc((size_t)(N + 1) * 4, 4);
  int*    colb      = (int*)walloc((size_t)(E + N) * 4, 4);
  int*    pairs     = (int*)walloc((size_t)E * 4, 4);
  int*    hist_part = (int*)walloc((size_t)nbHist * NBMAX * 4, 4);
  int*    pair_st   = (int*)walloc((NBMAX + 1) * 4, 4);
  int*    bucket_st = (int*)walloc((NBMAX + 1) * 4, 4);
  int*    pair_cur  = (int*)walloc((NBMAX + 1) * 4, 4);

  const dim3 b256(256);
  const dim3 gFront(nbEnc + nbPrep + nbHist);
  const dim3 gGemm(nbEnc);
  const dim3 gAgg((N + 3) / 4);
  const dim3 gNode((N + 255) / 256);

  // 1) front: encoder + W-prep + histogram partials (one launch)
  k_front<<<gFront, b256, 0, stream>>>(x, enc_W, enc_as, enc_ad, gh, as_buf, ad_buf,
                                       hid_W, hid_as, hid_ad, Wt_g, ei, hist_part,
                                       N, E, L, nbEnc, nbPrep);
  // 2) CSR: scan, append, build
  k_bscan2<<<dim3(1), dim3(1024), 0, stream>>>(hist_part, nbHist, pair_st, bucket_st,
                                               pair_cur, N, NB);
  k_bappend<<<dim3(nbHist), dim3(1024), 0, stream>>>(ei, pair_cur, pairs, E, NB);
  k_bbuild<<<dim3(NB), dim3(1024), 0, stream>>>(pairs, pair_st, bucket_st, row_ptr, colb, N, NB);

  // 3) encoder agg (act=1)
  k_agg128<<<gAgg, b256, 0, stream>>>(row_ptr, colb, as_buf, ad_buf, gh, enc_b, hh, N, 1,
                                      0, nullptr, nullptr, nullptr, nullptr, nullptr);

  // 4) hidden layers; last agg fuses the decoder GEMM
  for (int l = 0; l < L; ++l) {
    k_gemm_hid_mfma<<<gGemm, b256, 0, stream>>>(hh, Wt_g + (size_t)l * 144 * 128,
                                                gh, as_buf, ad_buf, N);
    int dec = (l == L - 1) ? 1 : 0;
    k_agg128<<<gAgg, b256, 0, stream>>>(row_ptr, colb, as_buf, ad_buf, gh,
                                        hid_b + (size_t)l * 128, hh, N, 0,
                                        dec, dec_W, dec_as, dec_ad, g4, adn);
  }

  // 5) decoder aggregation
  k_dec_agg<<<gNode, b256, 0, stream>>>(row_ptr, colb, adn, g4, dec_b,
                                        (float*)d_out, N);
}

// Round 13
// 353.582 us; speedup vs baseline: 2.2134x; 1.0356x over previous
//
#include <hip/hip_runtime.h>
#include <hip/hip_fp16.h>
#include <float.h>
#include <math.h>

#define NEG_ATT 0.2f
#define NEG_ACT 0.01f
#define BK 512      // nodes per CSR bucket (bucket = dst >> 9)
#define NBMAX 128   // max buckets supported (N <= 65536)

__device__ __forceinline__ float lrelu(float v, float s) { return v >= 0.f ? v : s * v; }

struct __align__(16) H8 { __half2 a, b, c, d; };
struct __align__(8)  H4 { __half2 x, y; };

typedef _Float16 f16;
typedef f16 f16x8 __attribute__((ext_vector_type(8)));
typedef float f32x4 __attribute__((ext_vector_type(4)));

// ============ FRONT mega-kernel: encoder GEMM | W-prep | bucket histogram ============
__global__ __launch_bounds__(256) void k_front(
    const float* __restrict__ x, const float* __restrict__ W,
    const float* __restrict__ a_src, const float* __restrict__ a_dst,
    __half* __restrict__ gh, float* __restrict__ as_out, float* __restrict__ ad_out,
    const float* __restrict__ hid_W, const float* __restrict__ hid_as,
    const float* __restrict__ hid_ad, __half* __restrict__ Wt,
    const int* __restrict__ ei, int* __restrict__ hist_part,
    int N, int E, int L, int nbEnc, int nbPrep) {
  __shared__ float sh[16 * 128 + 64 * 20];   // 13.3 KB, role-dependent reuse
  int tid = threadIdx.x;
  int bid = blockIdx.x;

  if (bid >= nbEnc + nbPrep) {
    // ---- histogram partials: 1024 edges/block, LDS-only, full overwrite ----
    int* lc = (int*)sh;
    if (tid < NBMAX) lc[tid] = 0;
    __syncthreads();
    int base = (bid - nbEnc - nbPrep) * 1024;
    #pragma unroll
    for (int j = 0; j < 4; ++j) {
      int e = base + j * 256 + tid;
      if (e < E) atomicAdd(&lc[ei[E + e] >> 9], 1);
    }
    __syncthreads();
    if (tid < NBMAX) hist_part[(size_t)(bid - nbEnc - nbPrep) * NBMAX + tid] = lc[tid];
    return;
  }
  if (bid >= nbEnc) {
    // ---- W prep for all hidden layers (rows 0-127 = W^T, 128-143 = W@[a_src|a_dst]) ----
    int idx = (bid - nbEnc) * 256 + tid;
    if (idx < L * 144 * 128) {
      int l = idx / (144 * 128);
      int rem = idx - l * 144 * 128;
      int r = rem >> 7, kk = rem & 127;
      const float* Wl = hid_W + (size_t)l * 128 * 128;
      float v;
      if (r < 128) {
        v = Wl[kk * 128 + r];
      } else {
        int hd = r - 128;
        const float* a = (hd < 8) ? (hid_as + (size_t)l * 128) : (hid_ad + (size_t)l * 128);
        int h2 = hd & 7;
        v = 0.f;
        #pragma unroll
        for (int c = 0; c < 16; ++c) v += Wl[kk * 128 + h2 * 16 + c] * a[h2 * 16 + c];
      }
      Wt[(size_t)l * 144 * 128 + r * 128 + kk] = __float2half(v);
    }
    return;
  }

  // ---- encoder GEMM (N x 16 @ 16 x 128) ----
  const int K = 16, KP = 20;
  float* Wl = sh;              // 16*128
  float* xl = sh + 16 * 128;   // 64*20
  int n0 = bid * 64;
  for (int i = tid * 4; i < (K << 6); i += 1024) {
    int row = i >> 4;
    int c = i & 15;
    float4 v = make_float4(0.f, 0.f, 0.f, 0.f);
    if (n0 + row < N) v = *(const float4*)(x + (size_t)(n0 + row) * K + c);
    *(float4*)(xl + row * KP + c) = v;
  }
  for (int i = tid * 4; i < 2048; i += 1024)
    *(float4*)(Wl + i) = *(const float4*)(W + i);
  __syncthreads();

  int ng = tid >> 4, jg = tid & 15;
  int jlo = jg * 4, jhi = 64 + jg * 4;
  float alo[4][4] = {}, ahi[4][4] = {};
  #pragma unroll 4
  for (int kk = 0; kk < K; ++kk) {
    const float4 wlo = *(const float4*)(Wl + (kk << 7) + jlo);
    const float4 whi = *(const float4*)(Wl + (kk << 7) + jhi);
    const float* xr = xl + (ng * 4) * KP + kk;
    #pragma unroll
    for (int i = 0; i < 4; ++i) {
      float xv = xr[i * KP];
      alo[i][0] += xv * wlo.x; alo[i][1] += xv * wlo.y;
      alo[i][2] += xv * wlo.z; alo[i][3] += xv * wlo.w;
      ahi[i][0] += xv * whi.x; ahi[i][1] += xv * whi.y;
      ahi[i][2] += xv * whi.z; ahi[i][3] += xv * whi.w;
    }
  }

  int hlo = jg >> 2, hhi = 4 + (jg >> 2), off4 = (jg & 3) * 4;
  #pragma unroll
  for (int i = 0; i < 4; ++i) {
    int n = n0 + ng * 4 + i;
    if (n >= N) break;
    H4 plo = { __floats2half2_rn(alo[i][0], alo[i][1]), __floats2half2_rn(alo[i][2], alo[i][3]) };
    H4 phi = { __floats2half2_rn(ahi[i][0], ahi[i][1]), __floats2half2_rn(ahi[i][2], ahi[i][3]) };
    *(H4*)(gh + (size_t)n * 128 + jlo) = plo;
    *(H4*)(gh + (size_t)n * 128 + jhi) = phi;
    float ps_lo = 0.f, pd_lo = 0.f, ps_hi = 0.f, pd_hi = 0.f;
    #pragma unroll
    for (int t = 0; t < 4; ++t) {
      ps_lo += alo[i][t] * a_src[hlo * 16 + off4 + t];
      pd_lo += alo[i][t] * a_dst[hlo * 16 + off4 + t];
      ps_hi += ahi[i][t] * a_src[hhi * 16 + off4 + t];
      pd_hi += ahi[i][t] * a_dst[hhi * 16 + off4 + t];
    }
    ps_lo += __shfl_xor(ps_lo, 1); ps_lo += __shfl_xor(ps_lo, 2);
    pd_lo += __shfl_xor(pd_lo, 1); pd_lo += __shfl_xor(pd_lo, 2);
    ps_hi += __shfl_xor(ps_hi, 1); ps_hi += __shfl_xor(ps_hi, 2);
    pd_hi += __shfl_xor(pd_hi, 1); pd_hi += __shfl_xor(pd_hi, 2);
    if ((jg & 3) == 0) {
      as_out[n * 8 + hlo] = ps_lo; ad_out[n * 8 + hlo] = pd_lo;
      as_out[n * 8 + hhi] = ps_hi; ad_out[n * 8 + hhi] = pd_hi;
    }
  }
}

// ======== bucket scan: reduce histogram partials, then exclusive scans ========
__global__ __launch_bounds__(1024) void k_bscan2(
    const int* __restrict__ hist_part, int nbHist,
    int* pair_st, int* bucket_st, int* pair_cur, int N, int NB) {
  __shared__ int part[1024];
  __shared__ int t1[128], t2[128];
  int tid = threadIdx.x;
  int colp = tid & 127, rg = tid >> 7;   // 8 row-groups
  int s = 0;
  for (int r = rg; r < nbHist; r += 8) s += hist_part[(size_t)r * NBMAX + colp];
  part[tid] = s;
  __syncthreads();
  int c = 0, nodesb = 0;
  if (tid < 128) {
    #pragma unroll
    for (int j = 0; j < 8; ++j) c += part[j * 128 + tid];
    if (tid < NB) {
      int base = tid * BK;
      nodesb = (N - base < BK) ? (N - base) : BK;
    }
    t1[tid] = c;
    t2[tid] = c + nodesb;
  }
  __syncthreads();
  for (int off = 1; off < 128; off <<= 1) {
    int a = 0, b = 0;
    if (tid < 128 && tid >= off) { a = t1[tid - off]; b = t2[tid - off]; }
    __syncthreads();
    if (tid < 128) { t1[tid] += a; t2[tid] += b; }
    __syncthreads();
  }
  if (tid < NB) {
    int ps = t1[tid] - c, bs = t2[tid] - (c + nodesb);
    pair_st[tid] = ps; pair_cur[tid] = ps; bucket_st[tid] = bs;
  }
  if (tid == 127) { pair_st[NB] = t1[127]; bucket_st[NB] = t2[127]; }
}

// append packed (src | local_dst<<17) into bucket regions
__global__ __launch_bounds__(1024) void k_bappend(const int* __restrict__ ei,
                                                  int* __restrict__ pair_cur,
                                                  int* __restrict__ pairs, int E, int NB) {
  __shared__ int lc[NBMAX], lb[NBMAX];
  int tid = threadIdx.x;
  if (tid < NB) lc[tid] = 0;
  __syncthreads();
  int e = blockIdx.x * 1024 + tid;
  int b = 0, r = 0, s = 0, d = 0;
  bool valid = e < E;
  if (valid) {
    s = ei[e]; d = ei[E + e]; b = d >> 9;
    r = atomicAdd(&lc[b], 1);
  }
  __syncthreads();
  if (tid < NB && lc[tid]) lb[tid] = atomicAdd(&pair_cur[tid], lc[tid]);
  __syncthreads();
  if (valid) pairs[lb[b] + r] = s | ((d & (BK - 1)) << 17);
}

// per-bucket: LDS degree count + wave-shuffle scan (3 barriers, was 20) + scatter
__global__ __launch_bounds__(1024) void k_bbuild(const int* __restrict__ pairs,
    const int* __restrict__ pair_start, const int* __restrict__ bucket_start,
    int* __restrict__ row_ptr, int* __restrict__ colb, int N, int NB) {
  __shared__ int deg[BK], cur[BK];
  __shared__ int wsum[16];
  int b = blockIdx.x, tid = threadIdx.x;
  int base = b * BK;
  int nodesb = (N - base < BK) ? (N - base) : BK;
  if (tid < BK) deg[tid] = (tid < nodesb) ? 1 : 0;  // self loop
  __syncthreads();
  int p0 = pair_start[b], p1 = pair_start[b + 1];
  for (int p = p0 + tid; p < p1; p += 1024)
    atomicAdd(&deg[pairs[p] >> 17], 1);
  __syncthreads();

  int v = (tid < BK) ? deg[tid] : 0;
  int lane = tid & 63, wv = tid >> 6;
  // wave-level inclusive scan (64-lane shfl_up)
  int sc = v;
  #pragma unroll
  for (int off = 1; off < 64; off <<= 1) {
    int t = __shfl_up(sc, off);
    if (lane >= off) sc += t;
  }
  if (lane == 63) wsum[wv] = sc;
  __syncthreads();
  if (tid < 16) {  // exclusive scan of the 16 wave sums (within one wave)
    int ws = wsum[tid];
    int scw = ws;
    #pragma unroll
    for (int off = 1; off < 16; off <<= 1) {
      int t = __shfl_up(scw, off, 16);
      if (tid >= off) scw += t;
    }
    wsum[tid] = scw - ws;  // exclusive
  }
  __syncthreads();
  int ex = sc - v + wsum[wv];  // exclusive prefix over the whole block

  int bs = bucket_start[b];
  if (tid < nodesb) {
    row_ptr[base + tid] = bs + ex;
    colb[bs + ex] = base + tid;  // self loop at segment head
    cur[tid] = ex + 1;
  }
  if (b == 0 && tid == 0) row_ptr[N] = bucket_start[NB];
  __syncthreads();
  for (int p = p0 + tid; p < p1; p += 1024) {
    int pr = pairs[p];
    int r = atomicAdd(&cur[pr >> 17], 1);
    colb[bs + r] = pr & 0x1FFFF;
  }
}

// ---------------- hidden GEMM via MFMA fp16 (N x 128 @ 128 x 144) ----------------
__global__ __launch_bounds__(256) void k_gemm_hid_mfma(
    const __half* __restrict__ xh_g, const __half* __restrict__ Wt_g,
    __half* __restrict__ gh, float* __restrict__ as_out, float* __restrict__ ad_out,
    int N) {
  __shared__ __half xh[64][136];
  __shared__ __half wt[144][136];
  int tid = threadIdx.x;
  int n0 = blockIdx.x * 64;

  for (int i = tid; i < 1024; i += 256) {      // x tile: 64 x 128 halves
    int row = i >> 4, c8 = (i & 15) * 8;
    float4 v = make_float4(0.f, 0.f, 0.f, 0.f);
    if (n0 + row < N) v = *(const float4*)(xh_g + (size_t)(n0 + row) * 128 + c8);
    *(float4*)(&xh[row][c8]) = v;
  }
  for (int i = tid; i < 2304; i += 256) {      // Wt: 144 x 128 halves
    int row = i >> 4, c8 = (i & 15) * 8;
    float4 v = *(const float4*)(Wt_g + (size_t)row * 128 + c8);
    *(float4*)(&wt[row][c8]) = v;
  }
  __syncthreads();

  int wave = tid >> 6, lane = tid & 63;
  int m = lane & 15, quad = lane >> 4;
  f32x4 acc[9] = {};
  #pragma unroll
  for (int kb = 0; kb < 128; kb += 32) {
    f16x8 a = *(const f16x8*)(&xh[wave * 16 + m][kb + quad * 8]);
    #pragma unroll
    for (int t = 0; t < 9; ++t) {
      f16x8 b = *(const f16x8*)(&wt[t * 16 + m][kb + quad * 8]);
      acc[t] = __builtin_amdgcn_mfma_f32_16x16x32_f16(a, b, acc[t], 0, 0, 0);
    }
  }

  // epilogue: tiles 0-7 -> gh fp16; tile 8 -> alphas fp32
  #pragma unroll
  for (int r = 0; r < 4; ++r) {
    int node = n0 + wave * 16 + quad * 4 + r;
    if (node >= N) continue;
    #pragma unroll
    for (int t = 0; t < 8; ++t)
      gh[(size_t)node * 128 + t * 16 + m] = __float2half(acc[t][r]);
    float v = acc[8][r];
    if (m < 8) as_out[node * 8 + m] = v;
    else       ad_out[node * 8 + (m - 8)] = v;
  }
}

// ---------------- aggregation (r10 config): single-pass, fp32 accum ----------------
// One wave/node, quarter-wave per edge (16 lanes x 16 B), 4 edges/instr,
// 16 edges per unrolled iter (4 H8 + 4 as in flight/lane). den fp32.
// dec==1: fused decoder GEMM epilogue.
__global__ __launch_bounds__(256) void k_agg128(
    const int* __restrict__ row_ptr, const int* __restrict__ col,
    const float* __restrict__ as, const float* __restrict__ ad,
    const __half* __restrict__ gh, const float* __restrict__ bias,
    __half* __restrict__ out, int N, int act,
    int dec, const float* __restrict__ dWd, const float* __restrict__ dasd,
    const float* __restrict__ dadd, float4* __restrict__ g4, float* __restrict__ adn) {
  int wid = threadIdx.x >> 6;
  int lane = threadIdx.x & 63;
  int n = blockIdx.x * 4 + wid;
  bool active = n < N;
  int nc = active ? n : 0;
  int s0 = active ? row_ptr[nc] : 0;
  int s1 = active ? row_ptr[nc + 1] : 0;

  int q = lane >> 4, l16 = lane & 15;
  int c0 = l16 * 8, hq = l16 >> 1;
  float adq = ad[nc * 8 + hq];
  const __half* gq = gh + c0;
  const float* asq = as + hq;
  float den = 0.f;
  float t0 = 0.f, t1 = 0.f, t2 = 0.f, t3 = 0.f, t4 = 0.f, t5 = 0.f, t6 = 0.f, t7 = 0.f;

  int b = s0;
  for (; b + 16 <= s1; b += 16) {   // 16 edges/wave iter; 4 H8 + 4 as in flight/lane
    int e0 = b + q, e1 = b + 4 + q, e2 = b + 8 + q, e3 = b + 12 + q;
    int sa = col[e0], sb = col[e1], sc = col[e2], sd = col[e3];
    float aa = asq[sa * 8], ab = asq[sb * 8], ac = asq[sc * 8], ae = asq[sd * 8];
    H8 ha = *(const H8*)(gq + (size_t)sa * 128);
    H8 hb = *(const H8*)(gq + (size_t)sb * 128);
    H8 hc = *(const H8*)(gq + (size_t)sc * 128);
    H8 hd = *(const H8*)(gq + (size_t)sd * 128);
    float wa = __expf(lrelu(aa + adq, NEG_ATT));
    float wb = __expf(lrelu(ab + adq, NEG_ATT));
    float wc = __expf(lrelu(ac + adq, NEG_ATT));
    float wd = __expf(lrelu(ae + adq, NEG_ATT));
    den += wa + wb + wc + wd;
    float2 f;
    f = __half22float2(ha.a); t0 += wa * f.x; t1 += wa * f.y;
    f = __half22float2(ha.b); t2 += wa * f.x; t3 += wa * f.y;
    f = __half22float2(ha.c); t4 += wa * f.x; t5 += wa * f.y;
    f = __half22float2(ha.d); t6 += wa * f.x; t7 += wa * f.y;
    f = __half22float2(hb.a); t0 += wb * f.x; t1 += wb * f.y;
    f = __half22float2(hb.b); t2 += wb * f.x; t3 += wb * f.y;
    f = __half22float2(hb.c); t4 += wb * f.x; t5 += wb * f.y;
    f = __half22float2(hb.d); t6 += wb * f.x; t7 += wb * f.y;
    f = __half22float2(hc.a); t0 += wc * f.x; t1 += wc * f.y;
    f = __half22float2(hc.b); t2 += wc * f.x; t3 += wc * f.y;
    f = __half22float2(hc.c); t4 += wc * f.x; t5 += wc * f.y;
    f = __half22float2(hc.d); t6 += wc * f.x; t7 += wc * f.y;
    f = __half22float2(hd.a); t0 += wd * f.x; t1 += wd * f.y;
    f = __half22float2(hd.b); t2 += wd * f.x; t3 += wd * f.y;
    f = __half22float2(hd.c); t4 += wd * f.x; t5 += wd * f.y;
    f = __half22float2(hd.d); t6 += wd * f.x; t7 += wd * f.y;
  }
  for (; b + 4 <= s1; b += 4) {     // 4 edges / wave iter
    int e0 = b + q;
    int sa = col[e0];
    float aa = asq[sa * 8];
    H8 ha = *(const H8*)(gq + (size_t)sa * 128);
    float wa = __expf(lrelu(aa + adq, NEG_ATT));
    den += wa;
    float2 f;
    f = __half22float2(ha.a); t0 += wa * f.x; t1 += wa * f.y;
    f = __half22float2(ha.b); t2 += wa * f.x; t3 += wa * f.y;
    f = __half22float2(ha.c); t4 += wa * f.x; t5 += wa * f.y;
    f = __half22float2(ha.d); t6 += wa * f.x; t7 += wa * f.y;
  }
  if (b + q < s1) {                 // masked remainder (<4 edges)
    int e0 = b + q;
    int sa = col[e0];
    float aa = asq[sa * 8];
    H8 ha = *(const H8*)(gq + (size_t)sa * 128);
    float wa = __expf(lrelu(aa + adq, NEG_ATT));
    den += wa;
    float2 f;
    f = __half22float2(ha.a); t0 += wa * f.x; t1 += wa * f.y;
    f = __half22float2(ha.b); t2 += wa * f.x; t3 += wa * f.y;
    f = __half22float2(ha.c); t4 += wa * f.x; t5 += wa * f.y;
    f = __half22float2(ha.d); t6 += wa * f.x; t7 += wa * f.y;
  }

  den += __shfl_xor(den, 16); den += __shfl_xor(den, 32);
  t0 += __shfl_xor(t0, 16); t0 += __shfl_xor(t0, 32);
  t1 += __shfl_xor(t1, 16); t1 += __shfl_xor(t1, 32);
  t2 += __shfl_xor(t2, 16); t2 += __shfl_xor(t2, 32);
  t3 += __shfl_xor(t3, 16); t3 += __shfl_xor(t3, 32);
  t4 += __shfl_xor(t4, 16); t4 += __shfl_xor(t4, 32);
  t5 += __shfl_xor(t5, 16); t5 += __shfl_xor(t5, 32);
  t6 += __shfl_xor(t6, 16); t6 += __shfl_xor(t6, 32);
  t7 += __shfl_xor(t7, 16); t7 += __shfl_xor(t7, 32);

  float inv = 1.f / den;
  const float4 b0 = *(const float4*)(bias + c0);
  const float4 b1 = *(const float4*)(bias + c0 + 4);
  float o0 = t0 * inv + b0.x, o1 = t1 * inv + b0.y;
  float o2 = t2 * inv + b0.z, o3 = t3 * inv + b0.w;
  float o4 = t4 * inv + b1.x, o5 = t5 * inv + b1.y;
  float o6 = t6 * inv + b1.z, o7 = t7 * inv + b1.w;
  if (act) {
    o0 = lrelu(o0, NEG_ACT); o1 = lrelu(o1, NEG_ACT);
    o2 = lrelu(o2, NEG_ACT); o3 = lrelu(o3, NEG_ACT);
    o4 = lrelu(o4, NEG_ACT); o5 = lrelu(o5, NEG_ACT);
    o6 = lrelu(o6, NEG_ACT); o7 = lrelu(o7, NEG_ACT);
  }
  if (!dec) {
    if (active && q == 0) {
      H8 pk = { __floats2half2_rn(o0, o1), __floats2half2_rn(o2, o3),
                __floats2half2_rn(o4, o5), __floats2half2_rn(o6, o7) };
      *(H8*)(out + (size_t)n * 128 + c0) = pk;
    }
  } else {
    // fused decoder GEMM: partial 8-col dot, reduce across the 16 q==0 lanes.
    float ov[8] = {o0, o1, o2, o3, o4, o5, o6, o7};
    float p0 = 0.f, p1 = 0.f, p2 = 0.f;
    #pragma unroll
    for (int i = 0; i < 8; ++i) {
      float wv0 = dWd[(c0 + i) * 3], wv1 = dWd[(c0 + i) * 3 + 1], wv2 = dWd[(c0 + i) * 3 + 2];
      p0 += ov[i] * wv0; p1 += ov[i] * wv1; p2 += ov[i] * wv2;
    }
    p0 += __shfl_xor(p0, 1); p0 += __shfl_xor(p0, 2); p0 += __shfl_xor(p0, 4); p0 += __shfl_xor(p0, 8);
    p1 += __shfl_xor(p1, 1); p1 += __shfl_xor(p1, 2); p1 += __shfl_xor(p1, 4); p1 += __shfl_xor(p1, 8);
    p2 += __shfl_xor(p2, 1); p2 += __shfl_xor(p2, 2); p2 += __shfl_xor(p2, 4); p2 += __shfl_xor(p2, 8);
    if (active && lane == 0) {
      float as_n = p0 * dasd[0] + p1 * dasd[1] + p2 * dasd[2];
      float ad_n = p0 * dadd[0] + p1 * dadd[1] + p2 * dadd[2];
      g4[n] = make_float4(p0, p1, p2, as_n);
      adn[n] = ad_n;
    }
  }
}

// ---------------- decoder aggregation, H=1 C=3, direct exp (no max) ----------------
__global__ __launch_bounds__(256) void k_dec_agg(
    const int* __restrict__ row_ptr, const int* __restrict__ col,
    const float* __restrict__ ad, const float4* __restrict__ g4,
    const float* __restrict__ b, float* __restrict__ out, int N) {
  int n = blockIdx.x * blockDim.x + threadIdx.x;
  if (n >= N) return;
  int s0 = row_ptr[n], s1 = row_ptr[n + 1];
  float adv = ad[n];
  float den = 0.f, A0 = 0.f, A1 = 0.f, A2 = 0.f;
  int k = s0;
  for (; k + 4 <= s1; k += 4) {
    int sa = col[k], sb = col[k + 1], sc = col[k + 2], sd = col[k + 3];
    float4 v0 = g4[sa], v1 = g4[sb], v2 = g4[sc], v3 = g4[sd];
    float w0 = __expf(lrelu(v0.w + adv, NEG_ATT));
    float w1 = __expf(lrelu(v1.w + adv, NEG_ATT));
    float w2 = __expf(lrelu(v2.w + adv, NEG_ATT));
    float w3 = __expf(lrelu(v3.w + adv, NEG_ATT));
    den += w0 + w1 + w2 + w3;
    A0 += w0 * v0.x + w1 * v1.x + w2 * v2.x + w3 * v3.x;
    A1 += w0 * v0.y + w1 * v1.y + w2 * v2.y + w3 * v3.y;
    A2 += w0 * v0.z + w1 * v1.z + w2 * v2.z + w3 * v3.z;
  }
  for (; k < s1; ++k) {
    float4 v = g4[col[k]];
    float w = __expf(lrelu(v.w + adv, NEG_ATT));
    den += w;
    A0 += w * v.x; A1 += w * v.y; A2 += w * v.z;
  }
  float inv = 1.f / den;
  out[(size_t)n * 3]     = A0 * inv + b[0];
  out[(size_t)n * 3 + 1] = A1 * inv + b[1];
  out[(size_t)n * 3 + 2] = A2 * inv + b[2];
}

// ---------------- host ----------------
extern "C" void kernel_launch(void* const* d_in, const int* in_sizes, int n_in,
                              void* d_out, int out_size, void* d_ws, size_t ws_size,
                              hipStream_t stream) {
  const float* x      = (const float*)d_in[0];
  const int*   ei     = (const int*)d_in[1];
  const float* enc_W  = (const float*)d_in[2];
  const float* enc_as = (const float*)d_in[3];
  const float* enc_ad = (const float*)d_in[4];
  const float* enc_b  = (const float*)d_in[5];
  const float* hid_W  = (const float*)d_in[6];
  const float* hid_as = (const float*)d_in[7];
  const float* hid_ad = (const float*)d_in[8];
  const float* hid_b  = (const float*)d_in[9];
  const float* dec_W  = (const float*)d_in[10];
  const float* dec_as = (const float*)d_in[11];
  const float* dec_ad = (const float*)d_in[12];
  const float* dec_b  = (const float*)d_in[13];

  const int N = in_sizes[0] / 16;
  const int E = in_sizes[1] / 2;
  const int L = in_sizes[6] / (128 * 128);
  const int NB = (N + BK - 1) / BK;  // assumed <= NBMAX (N <= 65536)

  // workspace carve-out
  char* wbase = (char*)d_ws;
  size_t woff = 0;
  auto walloc = [&](size_t bytes, size_t align) -> void* {
    woff = (woff + align - 1) & ~(align - 1);
    void* p = wbase + woff;
    woff += bytes;
    return p;
  };
  const int nbEnc  = (N + 63) / 64;
  const int nbPrep = (L * 144 * 128 + 255) / 256;
  const int nbHist = (E + 1023) / 1024;

  __half* gh        = (__half*)walloc((size_t)N * 128 * 2, 16);  // pre-agg features
  __half* hh        = (__half*)walloc((size_t)N * 128 * 2, 16);  // post-agg features
  float*  as_buf    = (float*)walloc((size_t)N * 8 * 4, 16);
  float*  ad_buf    = (float*)walloc((size_t)N * 8 * 4, 16);
  float4* g4        = (float4*)walloc((size_t)N * 16, 16);
  float*  adn       = (float*)walloc((size_t)N * 4, 16);
  __half* Wt_g      = (__half*)walloc((size_t)3 * 144 * 128 * 2, 16);
  int*    row_ptr   = (int*)walloc((size_t)(N + 1) * 4, 4);
  int*    colb      = (int*)walloc((size_t)(E + N) * 4, 4);
  int*    pairs     = (int*)walloc((size_t)E * 4, 4);
  int*    hist_part = (int*)walloc((size_t)nbHist * NBMAX * 4, 4);
  int*    pair_st   = (int*)walloc((NBMAX + 1) * 4, 4);
  int*    bucket_st = (int*)walloc((NBMAX + 1) * 4, 4);
  int*    pair_cur  = (int*)walloc((NBMAX + 1) * 4, 4);

  const dim3 b256(256);
  const dim3 gFront(nbEnc + nbPrep + nbHist);
  const dim3 gGemm(nbEnc);
  const dim3 gAgg((N + 3) / 4);
  const dim3 gNode((N + 255) / 256);

  // 1) front: encoder + W-prep + histogram partials (one launch)
  k_front<<<gFront, b256, 0, stream>>>(x, enc_W, enc_as, enc_ad, gh, as_buf, ad_buf,
                                       hid_W, hid_as, hid_ad, Wt_g, ei, hist_part,
                                       N, E, L, nbEnc, nbPrep);
  // 2) CSR: scan, append, build
  k_bscan2<<<dim3(1), dim3(1024), 0, stream>>>(hist_part, nbHist, pair_st, bucket_st,
                                               pair_cur, N, NB);
  k_bappend<<<dim3(nbHist), dim3(1024), 0, stream>>>(ei, pair_cur, pairs, E, NB);
  k_bbuild<<<dim3(NB), dim3(1024), 0, stream>>>(pairs, pair_st, bucket_st, row_ptr, colb, N, NB);

  // 3) encoder agg (act=1)
  k_agg128<<<gAgg, b256, 0, stream>>>(row_ptr, colb, as_buf, ad_buf, gh, enc_b, hh, N, 1,
                                      0, nullptr, nullptr, nullptr, nullptr, nullptr);

  // 4) hidden layers; last agg fuses the decoder GEMM
  for (int l = 0; l < L; ++l) {
    k_gemm_hid_mfma<<<gGemm, b256, 0, stream>>>(hh, Wt_g + (size_t)l * 144 * 128,
                                                gh, as_buf, ad_buf, N);
    int dec = (l == L - 1) ? 1 : 0;
    k_agg128<<<gAgg, b256, 0, stream>>>(row_ptr, colb, as_buf, ad_buf, gh,
                                        hid_b + (size_t)l * 128, hh, N, 0,
                                        dec, dec_W, dec_as, dec_ad, g4, adn);
  }

  // 5) decoder aggregation
  k_dec_agg<<<gNode, b256, 0, stream>>>(row_ptr, colb, adn, g4, dec_b,
                                        (float*)d_out, N);
}